// Round 1
// baseline (395.648 us; speedup 1.0000x reference)
//
#include <hip/hip_runtime.h>

// NoiseMix: out[r][d] = (rank(u[r][d]) >= floor(7*(1-lam[r]))) ? A[r][d] : B[r][d]
// rank = stable-argsort rank within the 7-element row.
//
// Layout trick: 7 floats/row is vector-hostile, so each thread owns 4 rows
// = 28 floats = 7 aligned float4 per array. All global traffic is dwordx4
// coalesced. Memory-bound: ~452 MiB total traffic -> ~75 us floor @6.3TB/s.

__global__ __launch_bounds__(256) void noisemix_kernel(
    const float4* __restrict__ A4,
    const float4* __restrict__ B4,
    const float4* __restrict__ L4,
    const float4* __restrict__ U4,
    float4* __restrict__ O4,
    int n_groups)
{
    const int t = blockIdx.x * blockDim.x + threadIdx.x;
    if (t >= n_groups) return;

    __align__(16) float u[28], a[28], b[28], o[28];

    const long base = (long)t * 7;
#pragma unroll
    for (int i = 0; i < 7; ++i) {
        *reinterpret_cast<float4*>(&u[4 * i]) = U4[base + i];
        *reinterpret_cast<float4*>(&a[4 * i]) = A4[base + i];
        *reinterpret_cast<float4*>(&b[4 * i]) = B4[base + i];
    }
    const float4 l4 = L4[t];
    const float lam[4] = {l4.x, l4.y, l4.z, l4.w};

#pragma unroll
    for (int r = 0; r < 4; ++r) {
        // num_zero = floor(7*(1-lam)) -- identical f32 ops to the reference.
        const int num_zero = (int)floorf(7.0f * (1.0f - lam[r]));

        int rank[7] = {0, 0, 0, 0, 0, 0, 0};
        // Stable-sort rank via complementary pair compares:
        // for e<d: c = (u[e] <= u[d]) contributes to rank[d]; !c to rank[e].
        // This encodes the index tie-break of a stable argsort exactly.
#pragma unroll
        for (int d = 1; d < 7; ++d) {
#pragma unroll
            for (int e = 0; e < d; ++e) {
                const bool c = (u[r * 7 + e] <= u[r * 7 + d]);
                rank[d] += c ? 1 : 0;
                rank[e] += c ? 0 : 1;
            }
        }

#pragma unroll
        for (int d = 0; d < 7; ++d) {
            o[r * 7 + d] = (rank[d] >= num_zero) ? a[r * 7 + d] : b[r * 7 + d];
        }
    }

#pragma unroll
    for (int i = 0; i < 7; ++i) {
        O4[base + i] = *reinterpret_cast<const float4*>(&o[4 * i]);
    }
}

extern "C" void kernel_launch(void* const* d_in, const int* in_sizes, int n_in,
                              void* d_out, int out_size, void* d_ws, size_t ws_size,
                              hipStream_t stream) {
    const float4* A4 = (const float4*)d_in[0];   // noise_A [B,7] f32
    const float4* B4 = (const float4*)d_in[1];   // noise_B [B,7] f32
    const float4* L4 = (const float4*)d_in[2];   // lam [B] f32
    const float4* U4 = (const float4*)d_in[3];   // u [B,7] f32

    float4* O4 = (float4*)d_out;

    const int rows = in_sizes[2];      // B = 4194304 (divisible by 4)
    const int n_groups = rows / 4;     // 1048576 thread-groups of 4 rows

    const int block = 256;
    const int grid = (n_groups + block - 1) / block;

    noisemix_kernel<<<grid, block, 0, stream>>>(A4, B4, L4, U4, O4, n_groups);
}

// Round 2
// 355.208 us; speedup vs baseline: 1.1138x; 1.1138x over previous
//
#include <hip/hip_runtime.h>

// NoiseMix: out[r][d] = (rank(u[r][d]) >= floor(7*(1-lam[r]))) ? A[r][d] : B[r][d]
//
// R2 design: row structure is only needed for the 7-bit mask. Stage u via LDS
// (coalesced loads, stride-7 LDS reads = conflict-free), compute per-row mask
// bits, then stream A/B->out with perfectly lane-contiguous float4 traffic.
//
// Tile: 256 threads x 1024 rows = 7168 floats = 1792 float4 per array.
// LDS: 28 KiB u + 4 KiB masks = 32 KiB -> 5 blocks/CU.

#define ROWS_PER_BLOCK 1024
#define F4_PER_BLOCK   1792   // ROWS_PER_BLOCK*7/4
#define F4_PER_THREAD  7      // F4_PER_BLOCK/256

__global__ __launch_bounds__(256) void noisemix_kernel(
    const float4* __restrict__ A4,
    const float4* __restrict__ B4,
    const float*  __restrict__ lam,
    const float4* __restrict__ U4,
    float4* __restrict__ O4)
{
    __shared__ float    u_s[ROWS_PER_BLOCK * 7];   // 28 KiB
    __shared__ unsigned mask_s[ROWS_PER_BLOCK];    // 4 KiB

    const int tid = threadIdx.x;
    const long tile_f4  = (long)blockIdx.x * F4_PER_BLOCK;
    const long tile_row = (long)blockIdx.x * ROWS_PER_BLOCK;

    // ---- Phase 1: stage u into LDS (lane-contiguous global, linear LDS) ----
#pragma unroll
    for (int i = 0; i < F4_PER_THREAD; ++i) {
        const int f = i * 256 + tid;
        *reinterpret_cast<float4*>(&u_s[4 * f]) = U4[tile_f4 + f];
    }
    __syncthreads();

    // ---- Phase 2: per-row rank -> 7-bit mask ----
#pragma unroll
    for (int j = 0; j < ROWS_PER_BLOCK / 256; ++j) {
        const int row = tid + j * 256;
        const float lm = lam[tile_row + row];
        // identical f32 ops to the reference: floor(7*(1-lam))
        const int num_zero = (int)floorf(7.0f * (1.0f - lm));

        float u[7];
#pragma unroll
        for (int d = 0; d < 7; ++d) u[d] = u_s[7 * row + d];  // stride 7: conflict-free

        int rank[7] = {0, 0, 0, 0, 0, 0, 0};
        // Stable-argsort rank via complementary pair compares (ties -> index order).
#pragma unroll
        for (int d = 1; d < 7; ++d) {
#pragma unroll
            for (int e = 0; e < d; ++e) {
                const bool c = (u[e] <= u[d]);
                rank[d] += c ? 1 : 0;
                rank[e] += c ? 0 : 1;
            }
        }

        unsigned bits = 0;
#pragma unroll
        for (int d = 0; d < 7; ++d) bits |= (rank[d] >= num_zero ? 1u : 0u) << d;
        mask_s[row] = bits;
    }
    __syncthreads();

    // ---- Phase 3: stream A/B -> out, all lane-contiguous float4 ----
#pragma unroll
    for (int i = 0; i < F4_PER_THREAD; ++i) {
        const int f = i * 256 + tid;
        const float4 a = A4[tile_f4 + f];
        const float4 b = B4[tile_f4 + f];

        const int e0 = 4 * f;                 // local element index, < 7168
        int row = (e0 * 9363) >> 16;          // e0/7 (valid for e0 < 13107)
        int d   = e0 - 7 * row;

        float4 o;
        float* op = &o.x;
        const float* ap = &a.x;
        const float* bp = &b.x;
        unsigned m = mask_s[row];
#pragma unroll
        for (int c = 0; c < 4; ++c) {
            op[c] = ((m >> d) & 1u) ? ap[c] : bp[c];
            if (++d == 7) { d = 0; ++row; m = mask_s[row]; }
        }
        O4[tile_f4 + f] = o;
    }
}

extern "C" void kernel_launch(void* const* d_in, const int* in_sizes, int n_in,
                              void* d_out, int out_size, void* d_ws, size_t ws_size,
                              hipStream_t stream) {
    const float4* A4  = (const float4*)d_in[0];   // noise_A [B,7] f32
    const float4* B4  = (const float4*)d_in[1];   // noise_B [B,7] f32
    const float*  lam = (const float*)d_in[2];    // lam [B] f32
    const float4* U4  = (const float4*)d_in[3];   // u [B,7] f32

    float4* O4 = (float4*)d_out;

    const int rows = in_sizes[2];                 // B = 4194304, divisible by 1024
    const int grid = rows / ROWS_PER_BLOCK;       // 4096 blocks

    noisemix_kernel<<<grid, 256, 0, stream>>>(A4, B4, lam, U4, O4);
}

// Round 4
// 334.291 us; speedup vs baseline: 1.1835x; 1.0626x over previous
//
#include <hip/hip_runtime.h>

// NoiseMix: out[r][d] = (rank(u[r][d]) >= floor(7*(1-lam[r]))) ? A[r][d] : B[r][d]
//
// R4 = R3 with native vector type for the nontemporal builtins.
//  K1 (mask): stage u via LDS (coalesced), compute per-row 7-bit mask, write
//     one uchar/row to d_ws (4 MiB).  ~128 MiB read.
//  K2 (mix): pure elementwise stream. thread = 4 lane-contiguous float4;
//     row via magic /7; mask byte from d_ws (LLC-resident broadcast).
//     ~224 MiB read + 112 MiB write, zero LDS, full occupancy.

typedef float vfloat4 __attribute__((ext_vector_type(4)));

#define ROWS_PER_BLOCK 1024
#define F4_PER_BLOCK   1792   // ROWS_PER_BLOCK*7/4
#define F4_PER_THREAD  7

__device__ __forceinline__ unsigned row_mask_bits(const float* u, float lm) {
    // num_zero = floor(7*(1-lam)) -- identical f32 ops to the reference.
    const int num_zero = (int)floorf(7.0f * (1.0f - lm));
    int rank[7] = {0, 0, 0, 0, 0, 0, 0};
    // Stable-argsort rank via complementary pair compares (ties -> index order).
#pragma unroll
    for (int d = 1; d < 7; ++d)
#pragma unroll
        for (int e = 0; e < d; ++e) {
            const bool c = (u[e] <= u[d]);
            rank[d] += c ? 1 : 0;
            rank[e] += c ? 0 : 1;
        }
    unsigned bits = 0;
#pragma unroll
    for (int d = 0; d < 7; ++d) bits |= (rank[d] >= num_zero ? 1u : 0u) << d;
    return bits;
}

// ---- K1: masks ----
__global__ __launch_bounds__(256) void mask_kernel(
    const vfloat4* __restrict__ U4,
    const float*  __restrict__ lam,
    unsigned char* __restrict__ mask_g)
{
    __shared__ float u_s[ROWS_PER_BLOCK * 7];   // 28 KiB

    const int tid = threadIdx.x;
    const long tile_f4  = (long)blockIdx.x * F4_PER_BLOCK;
    const long tile_row = (long)blockIdx.x * ROWS_PER_BLOCK;

#pragma unroll
    for (int i = 0; i < F4_PER_THREAD; ++i) {
        const int f = i * 256 + tid;
        *reinterpret_cast<vfloat4*>(&u_s[4 * f]) =
            __builtin_nontemporal_load(&U4[tile_f4 + f]);
    }
    __syncthreads();

#pragma unroll
    for (int j = 0; j < ROWS_PER_BLOCK / 256; ++j) {
        const int row = tid + j * 256;
        float u[7];
#pragma unroll
        for (int d = 0; d < 7; ++d) u[d] = u_s[7 * row + d];  // stride 7: conflict-free
        const float lm = lam[tile_row + row];
        mask_g[tile_row + row] = (unsigned char)row_mask_bits(u, lm);
    }
}

// ---- K2: mix ----
#define MIX_IT 4   // float4 per thread

__global__ __launch_bounds__(256) void mix_kernel(
    const vfloat4* __restrict__ A4,
    const vfloat4* __restrict__ B4,
    const unsigned char* __restrict__ mask_g,
    vfloat4* __restrict__ O4)
{
    const long tile = (long)blockIdx.x * (256 * MIX_IT) + threadIdx.x;

    vfloat4 a[MIX_IT], b[MIX_IT];
#pragma unroll
    for (int j = 0; j < MIX_IT; ++j) {
        a[j] = __builtin_nontemporal_load(&A4[tile + j * 256]);
        b[j] = __builtin_nontemporal_load(&B4[tile + j * 256]);
    }

#pragma unroll
    for (int j = 0; j < MIX_IT; ++j) {
        const unsigned e0 = (unsigned)(4 * (tile + j * 256));
        const unsigned row0 = e0 / 7u;            // compiler magic-mul
        const int d = (int)(e0 - 7u * row0);
        // 4 consecutive elements span at most rows {row0, row0+1};
        // row0+1 only needed when d>=4, in which case it exists.
        const unsigned row1 = (d >= 4) ? row0 + 1 : row0;
        const unsigned mm = (unsigned)mask_g[row0] |
                            ((unsigned)mask_g[row1] << 7);

        vfloat4 o;
#pragma unroll
        for (int c = 0; c < 4; ++c)
            o[c] = ((mm >> (d + c)) & 1u) ? a[j][c] : b[j][c];
        __builtin_nontemporal_store(o, &O4[tile + j * 256]);
    }
}

// ---- Fallback (R2 fused kernel) if ws too small ----
__global__ __launch_bounds__(256) void noisemix_fused(
    const vfloat4* __restrict__ A4,
    const vfloat4* __restrict__ B4,
    const float*  __restrict__ lam,
    const vfloat4* __restrict__ U4,
    vfloat4* __restrict__ O4)
{
    __shared__ float    u_s[ROWS_PER_BLOCK * 7];
    __shared__ unsigned mask_s[ROWS_PER_BLOCK];

    const int tid = threadIdx.x;
    const long tile_f4  = (long)blockIdx.x * F4_PER_BLOCK;
    const long tile_row = (long)blockIdx.x * ROWS_PER_BLOCK;

#pragma unroll
    for (int i = 0; i < F4_PER_THREAD; ++i) {
        const int f = i * 256 + tid;
        *reinterpret_cast<vfloat4*>(&u_s[4 * f]) = U4[tile_f4 + f];
    }
    __syncthreads();

#pragma unroll
    for (int j = 0; j < ROWS_PER_BLOCK / 256; ++j) {
        const int row = tid + j * 256;
        float u[7];
#pragma unroll
        for (int d = 0; d < 7; ++d) u[d] = u_s[7 * row + d];
        mask_s[row] = row_mask_bits(u, lam[tile_row + row]);
    }
    __syncthreads();

#pragma unroll
    for (int i = 0; i < F4_PER_THREAD; ++i) {
        const int f = i * 256 + tid;
        const vfloat4 a = A4[tile_f4 + f];
        const vfloat4 b = B4[tile_f4 + f];
        const int e0 = 4 * f;
        int row = (e0 * 9363) >> 16;   // e0/7 for e0 < 13107
        int d   = e0 - 7 * row;
        vfloat4 o;
        unsigned m = mask_s[row];
#pragma unroll
        for (int c = 0; c < 4; ++c) {
            o[c] = ((m >> d) & 1u) ? a[c] : b[c];
            if (++d == 7) { d = 0; ++row; m = mask_s[row]; }
        }
        O4[tile_f4 + f] = o;
    }
}

extern "C" void kernel_launch(void* const* d_in, const int* in_sizes, int n_in,
                              void* d_out, int out_size, void* d_ws, size_t ws_size,
                              hipStream_t stream) {
    const vfloat4* A4  = (const vfloat4*)d_in[0];   // noise_A [B,7] f32
    const vfloat4* B4  = (const vfloat4*)d_in[1];   // noise_B [B,7] f32
    const float*   lam = (const float*)d_in[2];     // lam [B] f32
    const vfloat4* U4  = (const vfloat4*)d_in[3];   // u [B,7] f32
    vfloat4* O4 = (vfloat4*)d_out;

    const int rows = in_sizes[2];                   // B = 4194304

    if (ws_size >= (size_t)rows) {
        unsigned char* mask_g = (unsigned char*)d_ws;
        const int grid1 = rows / ROWS_PER_BLOCK;              // 4096
        mask_kernel<<<grid1, 256, 0, stream>>>(U4, lam, mask_g);

        const int total_f4 = (rows / 4) * 7;                  // 7340032
        const int grid2 = total_f4 / (256 * MIX_IT);          // 7168
        mix_kernel<<<grid2, 256, 0, stream>>>(A4, B4, mask_g, O4);
    } else {
        const int grid = rows / ROWS_PER_BLOCK;
        noisemix_fused<<<grid, 256, 0, stream>>>(A4, B4, lam, U4, O4);
    }
}